// Round 8
// baseline (63.928 us; speedup 1.0000x reference)
//
#include <hip/hip_runtime.h>
#include <math.h>

typedef unsigned long long u64;
typedef unsigned int u32;

#define NB   2
#define L0   4800
#define L1   4800
#define H1C  60
#define W1C  80
#define ROWS 8
#define RPB  (L0 / ROWS)          // 600 row-groups per batch
#define NBLK (NB * RPB)           // 1200 blocks
#define NT   256                  // 4 waves
#define NW   (NT / 64)
#define CH   1200                 // points per LDS chunk
#define CH4  (CH / 2)             // 600 float4 per chunk
// partials layout: k in [0,12): {Sm,Sl2,Ssl2,Ss,Sv,Ssq} x {word-mask, byte-mask}

__global__ __launch_bounds__(NT, 8) void s2ld_fused(
    const float* __restrict__ w_pt0,    // [NB][L0][2]
    const float* __restrict__ pt1,      // [NB][L1][2]
    const void*  __restrict__ maskp,    // [NB][L0] word- or byte-bool
    const float* __restrict__ score0,   // [NB][L0]
    const float* __restrict__ score1,   // [NB][L1]
    const float* __restrict__ scale0,   // [NB][2]
    const float* __restrict__ scale1,   // [NB][2]
    float*       __restrict__ partials, // [12][NBLK]
    u32*         __restrict__ counter,
    float*       __restrict__ out)      // [3]
{
    __shared__ float4 sA[CH4];          // 9600 B
    __shared__ float4 sB[CH4];          // 9600 B
    __shared__ float  redd[ROWS * NW];
    __shared__ int    redj[ROWS * NW];
    __shared__ float  fin[12 * NW];
    __shared__ int    slast;
    __shared__ u32    sbad;

    const int tid  = threadIdx.x;
    const int blk  = blockIdx.x;
    const int n    = blk / RPB;
    const int gi0  = n * L0 + (blk % RPB) * ROWS;
    const int lane = tid & 63;
    const int wv   = tid >> 6;

    const float4* p1 = (const float4*)(pt1 + (size_t)n * L1 * 2);
    const float4* p0 = (const float4*)(w_pt0 + (size_t)gi0 * 2);  // 4 float4

    // Per-row constants as NAMED scalars (arrays => scratch demotion, r2/r3).
    // Minimize s_j = |q_j|^2 - 2 p.q_j  (order == d2 order); ax=-2px, ay=-2py.
    float ax0,ax1,ax2,ax3,ax4,ax5,ax6,ax7;
    float ay0,ay1,ay2,ay3,ay4,ay5,ay6,ay7;
    {
        float4 f;
        f=p0[0]; ax0=-2.0f*f.x; ay0=-2.0f*f.y; ax1=-2.0f*f.z; ay1=-2.0f*f.w;
        f=p0[1]; ax2=-2.0f*f.x; ay2=-2.0f*f.y; ax3=-2.0f*f.z; ay3=-2.0f*f.w;
        f=p0[2]; ax4=-2.0f*f.x; ay4=-2.0f*f.y; ax5=-2.0f*f.z; ay5=-2.0f*f.w;
        f=p0[3]; ax6=-2.0f*f.x; ay6=-2.0f*f.y; ax7=-2.0f*f.z; ay7=-2.0f*f.w;
    }
    float bd0=3e38f,bd1=3e38f,bd2=3e38f,bd3=3e38f,
          bd4=3e38f,bd5=3e38f,bd6=3e38f,bd7=3e38f;
    int   bj0=0,bj1=0,bj2=0,bj3=0,bj4=0,bj5=0,bj6=0,bj7=0;

#define STAGE(BUF, c) {                                               \
        BUF[tid]       = p1[(c) * CH4 + tid];                         \
        BUF[tid + 256] = p1[(c) * CH4 + tid + 256];                   \
        if (tid < CH4 - 512) BUF[tid + 512] = p1[(c) * CH4 + tid + 512]; }

#define DO_ROW(R) {                                                   \
        float s0 = fmaf(ax##R, q.x, fmaf(ay##R, q.y, c0));            \
        if (s0 < bd##R) { bd##R = s0; bj##R = j0; }                   \
        float s1 = fmaf(ax##R, q.z, fmaf(ay##R, q.w, c1));            \
        if (s1 < bd##R) { bd##R = s1; bj##R = j0 + 1; } }

#define COMPUTE(BUF, c)                                               \
    for (int j4 = tid; j4 < CH4; j4 += NT) {                          \
        const float4 q = BUF[j4];                                     \
        const float c0 = fmaf(q.x, q.x, q.y * q.y);                   \
        const float c1 = fmaf(q.z, q.z, q.w * q.w);                   \
        const int j0 = (c) * CH + 2 * j4;                             \
        DO_ROW(0) DO_ROW(1) DO_ROW(2) DO_ROW(3)                       \
        DO_ROW(4) DO_ROW(5) DO_ROW(6) DO_ROW(7)                       \
    }

    // double-buffered chunks; j ascends per thread => first-occurrence argmin
    STAGE(sA, 0);
    __syncthreads();
    STAGE(sB, 1); COMPUTE(sA, 0);
    __syncthreads();
    STAGE(sA, 2); COMPUTE(sB, 1);
    __syncthreads();
    STAGE(sB, 3); COMPUTE(sA, 2);
    __syncthreads();
    COMPUTE(sB, 3);
#undef STAGE
#undef DO_ROW
#undef COMPUTE

    // wave-level min+argmin per row, tie-break smaller j (first occurrence)
#define REDUCE_ROW(R) {                                               \
        float d = bd##R; int jj = bj##R;                              \
        for (int off = 32; off; off >>= 1) {                          \
            float od = __shfl_xor(d, off);                            \
            int   oj = __shfl_xor(jj, off);                           \
            if (od < d || (od == d && oj < jj)) { d = od; jj = oj; }  \
        }                                                             \
        if (lane == 0) { redd[R * NW + wv] = d; redj[R * NW + wv] = jj; } }

    REDUCE_ROW(0) REDUCE_ROW(1) REDUCE_ROW(2) REDUCE_ROW(3)
    REDUCE_ROW(4) REDUCE_ROW(5) REDUCE_ROW(6) REDUCE_ROW(7)
#undef REDUCE_ROW
    __syncthreads();

    // parallel epilogue: lane r (< 8, wave 0) handles row r
    if (tid < ROWS) {
        const int r = tid;
        float d = redd[r * NW + 0]; int jj = redj[r * NW + 0];
        #pragma unroll
        for (int w = 1; w < NW; ++w) {
            float od = redd[r * NW + w]; int oj = redj[r * NW + w];
            if (od < d || (od == d && oj < jj)) { d = od; jj = oj; }
        }
        const int gi = gi0 + r;
        const float2 q0 = ((const float2*)w_pt0)[gi];
        const float pp = fmaf(q0.x, q0.x, q0.y * q0.y);   // |p|^2
        const float l2 = sqrtf(fmaxf(d + pp, 0.0f));

        const float thr = 8.0f * scale0[n * 2 + 0];
        const float sxd = ((float)W1C * scale1[n * 2 + 0] * 8.0f - 1.0f) * 0.5f;
        const float syd = ((float)H1C * scale1[n * 2 + 1] * 8.0f - 1.0f) * 0.5f;
        const float* im = score1 + (size_t)n * L1;

        const float mw = (((const u32*)maskp)[gi] != 0u) ? 1.0f : 0.0f;
        const float mb = (((const unsigned char*)maskp)[gi] != 0) ? 1.0f : 0.0f;
        const float inthr = (l2 <= thr) ? 1.0f : 0.0f;

        const float s0v  = score0[gi];
        const float ssum = im[jj] + s0v;

        const float gx = (q0.x / sxd) * 0.5f * (float)(W1C - 1);
        const float gy = (q0.y / syd) * 0.5f * (float)(H1C - 1);
        const float x0 = floorf(gx), y0 = floorf(gy);
        const float x1 = x0 + 1.0f,  y1 = y0 + 1.0f;
        const float wx1 = gx - x0, wx0 = 1.0f - wx1;
        const float wy1 = gy - y0, wy0 = 1.0f - wy1;

        auto corner = [&](float xf, float yf) -> float {
            bool inb = (xf >= 0.0f) && (xf <= (float)(W1C - 1)) &&
                       (yf >= 0.0f) && (yf <= (float)(H1C - 1));
            int xc = (int)fminf(fmaxf(xf, 0.0f), (float)(W1C - 1));
            int yc = (int)fminf(fmaxf(yf, 0.0f), (float)(H1C - 1));
            float v = im[yc * W1C + xc];
            return inb ? v : 0.0f;
        };
        const float res = corner(x0, y0) * wx0 * wy0
                        + corner(x1, y0) * wx1 * wy0
                        + corner(x0, y1) * wx0 * wy1
                        + corner(x1, y1) * wx1 * wy1;
        const float dsc = res - s0v;
        const float dsq = dsc * dsc;

        const float dvw = inthr * mw, dvb = inthr * mb;
        float v0  = dvw,        v1 = l2 * dvw,  v2  = ssum * l2 * dvw;
        float v3  = ssum * dvw, v4 = mw,        v5  = dsq * mw;
        float v6  = dvb,        v7 = l2 * dvb,  v8  = ssum * l2 * dvb;
        float v9  = ssum * dvb, v10 = mb,       v11 = dsq * mb;
#define RED8(V) { V += __shfl_xor(V, 4); V += __shfl_xor(V, 2); V += __shfl_xor(V, 1); }
        RED8(v0) RED8(v1) RED8(v2) RED8(v3) RED8(v4)  RED8(v5)
        RED8(v6) RED8(v7) RED8(v8) RED8(v9) RED8(v10) RED8(v11)
#undef RED8
        if (tid == 0) {
            partials[ 0 * NBLK + blk] = v0;  partials[ 1 * NBLK + blk] = v1;
            partials[ 2 * NBLK + blk] = v2;  partials[ 3 * NBLK + blk] = v3;
            partials[ 4 * NBLK + blk] = v4;  partials[ 5 * NBLK + blk] = v5;
            partials[ 6 * NBLK + blk] = v6;  partials[ 7 * NBLK + blk] = v7;
            partials[ 8 * NBLK + blk] = v8;  partials[ 9 * NBLK + blk] = v9;
            partials[10 * NBLK + blk] = v10; partials[11 * NBLK + blk] = v11;
        }
    }

    // last-block-done finalize; (old % NBLK)==NBLK-1 fires exactly once per
    // call for ANY initial counter value (calls are stream-serialized).
    if (tid == 0) {
        __threadfence();
        u32 old = atomicAdd(counter, 1u);
        slast = ((old % (u32)NBLK) == (u32)(NBLK - 1)) ? 1 : 0;
    }
    __syncthreads();
    if (!slast) return;
    __threadfence();

    // mask format detection (first 2400 words in-bounds for all layouts)
    if (tid == 0) sbad = 0u;
    __syncthreads();
    {
        u32 bad = 0u;
        const u32* mwp = (const u32*)maskp;
        for (int i = tid; i < 2400; i += NT) {
            u32 w = mwp[i];
            if (w != 0u && w != 1u && w != 0x3f800000u) bad = 1u;
        }
        atomicOr(&sbad, bad);
        __syncthreads();
    }

    // reduce the 12 partial arrays (1200 entries each)
    for (int k = 0; k < 12; ++k) {
        float s = 0.0f;
        for (int rbl = tid; rbl < NBLK; rbl += NT) s += partials[k * NBLK + rbl];
        #pragma unroll
        for (int off = 32; off; off >>= 1) s += __shfl_xor(s, off);
        if (lane == 0) fin[k * NW + wv] = s;
    }
    __syncthreads();

    if (tid == 0) {
        const int o = (sbad == 0u) ? 0 : 6;   // word-format vs byte-format
        float S[6];
        #pragma unroll
        for (int k = 0; k < 6; ++k) {
            float s = 0.0f;
            #pragma unroll
            for (int w = 0; w < NW; ++w) s += fin[(o + k) * NW + w];
            S[k] = s;
        }
        const float den = fmaxf(S[0], 1.0f);
        const float lm  = S[1] / den;
        out[0] = lm;                              // loc_loss_mean
        out[1] = (S[2] - lm * S[3]) / den;        // rep_loss_mean
        out[2] = 2.0f * S[5] / fmaxf(S[4], 1.0f); // score_loss
    }
}

extern "C" void kernel_launch(void* const* d_in, const int* in_sizes, int n_in,
                              void* d_out, int out_size, void* d_ws, size_t ws_size,
                              hipStream_t stream) {
    const float* w_pt0  = (const float*)d_in[0];
    const float* pt1    = (const float*)d_in[1];
    const void*  maskp  =               d_in[2];
    const float* score0 = (const float*)d_in[3];
    const float* score1 = (const float*)d_in[4];
    // d_in[5] = image1 (zeros) -- unused
    const float* scale0 = (const float*)d_in[6];
    const float* scale1 = (const float*)d_in[7];

    u32*   counter  = (u32*)d_ws;
    float* partials = (float*)((char*)d_ws + 256);

    s2ld_fused<<<NBLK, NT, 0, stream>>>(w_pt0, pt1, maskp, score0, score1,
                                        scale0, scale1, partials, counter,
                                        (float*)d_out);
}

// Round 9
// 46.149 us; speedup vs baseline: 1.3852x; 1.3852x over previous
//
#include <hip/hip_runtime.h>
#include <math.h>

typedef unsigned int u32;

#define NB   2
#define L0   4800
#define L1   4800
#define H1C  60
#define W1C  80
#define ROWS 8
#define RPB  (L0 / ROWS)          // 600 row-groups per batch
#define NBLK (NB * RPB)           // 1200 blocks
#define NT   256                  // 4 waves
#define NW   (NT / 64)
#define L14  (L1 / 2)             // 2400 float4 per batch
// partials layout: k in [0,12): {Sm,Sl2,Ssl2,Ss,Sv,Ssq} x {word-mask, byte-mask}

// ---------------------------------------------------------------------------
// Main kernel: r1's proven shape (full-tile LDS, plain loops, VGPR~52, no
// spill) + ax/ay algebra + parallel 8-lane epilogue + XCD parity swizzle.
// NO atomics / threadfence (suspected 6-20us tail in fused variants).
// __launch_bounds__(256,4): cap 128 VGPR -- the unified no-spill condition
// (spill signature WRITE_SIZE=487KB appeared exactly when cap collapsed to 64).
// ---------------------------------------------------------------------------
__global__ __launch_bounds__(NT, 4) void s2ld_main(
    const float* __restrict__ w_pt0,    // [NB][L0][2]
    const float* __restrict__ pt1,      // [NB][L1][2]
    const void*  __restrict__ maskp,    // [NB][L0] word- or byte-bool
    const float* __restrict__ score0,   // [NB][L0]
    const float* __restrict__ score1,   // [NB][L1]
    const float* __restrict__ scale0,   // [NB][2]
    const float* __restrict__ scale1,   // [NB][2]
    float*       __restrict__ partials) // [12][NBLK]
{
    __shared__ float4 sF[L14];          // 38400 B
    __shared__ float  redd[ROWS * NW];
    __shared__ int    redj[ROWS * NW];

    const int tid  = threadIdx.x;
    const int blk  = blockIdx.x;
    // XCD parity swizzle: blockIdx round-robins XCDs, so blk&1 pins each XCD
    // to ONE batch -> halves cold-HBM duplication of pt1 across XCDs.
    const int n    = blk & 1;
    const int rg   = blk >> 1;          // row-group within batch, 0..599
    const int gi0  = n * L0 + rg * ROWS;
    const int lane = tid & 63;
    const int wv   = tid >> 6;

    const float4* p1 = (const float4*)(pt1 + (size_t)n * L1 * 2);
    const float2* p0 = (const float2*)(w_pt0 + (size_t)gi0 * 2);

    // stage full pt1 tile: 9 uniform + 1 masked load, all issued back-to-back
    #pragma unroll
    for (int k = 0; k < 9; ++k) sF[tid + k * 256] = p1[tid + k * 256];
    if (tid < L14 - 9 * 256) sF[tid + 9 * 256] = p1[tid + 9 * 256];

    // minimize s_j = |q_j|^2 - 2 p.q_j (same order as d2); ax=-2px, ay=-2py.
    float ax[ROWS], ay[ROWS];
    #pragma unroll
    for (int r = 0; r < ROWS; ++r) {
        float2 q = p0[r];
        ax[r] = -2.0f * q.x; ay[r] = -2.0f * q.y;
    }
    float bd[ROWS]; int bj[ROWS];
    #pragma unroll
    for (int r = 0; r < ROWS; ++r) { bd[r] = 3.0e38f; bj[r] = 0; }

    __syncthreads();

    // j ascends per thread => first-occurrence argmin within a thread;
    // cross-thread ties resolved (min val, then min j) in the reduce.
    for (int j4 = tid; j4 < L14; j4 += NT) {
        const float4 q = sF[j4];
        const float c0 = fmaf(q.x, q.x, q.y * q.y);
        const float c1 = fmaf(q.z, q.z, q.w * q.w);
        const int j0 = 2 * j4;
        #pragma unroll
        for (int r = 0; r < ROWS; ++r) {
            float s0 = fmaf(ax[r], q.x, fmaf(ay[r], q.y, c0));
            if (s0 < bd[r]) { bd[r] = s0; bj[r] = j0; }
            float s1 = fmaf(ax[r], q.z, fmaf(ay[r], q.w, c1));
            if (s1 < bd[r]) { bd[r] = s1; bj[r] = j0 + 1; }
        }
    }

    // wave-level min+argmin per row, tie-break smaller j (first occurrence)
    #pragma unroll
    for (int r = 0; r < ROWS; ++r) {
        float d = bd[r]; int jj = bj[r];
        #pragma unroll
        for (int off = 32; off; off >>= 1) {
            float od = __shfl_xor(d, off);
            int   oj = __shfl_xor(jj, off);
            if (od < d || (od == d && oj < jj)) { d = od; jj = oj; }
        }
        if (lane == 0) { redd[r * NW + wv] = d; redj[r * NW + wv] = jj; }
    }
    __syncthreads();

    // parallel epilogue: lane r (< 8, wave 0) handles row r. Query point is
    // RELOADED from global (L1-hot): indexing ax[tid] would demote the arrays
    // to scratch (rule #20 / round-2 regression).
    if (tid < ROWS) {
        const int r = tid;
        float d = redd[r * NW + 0]; int jj = redj[r * NW + 0];
        #pragma unroll
        for (int w = 1; w < NW; ++w) {
            float od = redd[r * NW + w]; int oj = redj[r * NW + w];
            if (od < d || (od == d && oj < jj)) { d = od; jj = oj; }
        }
        const int gi = gi0 + r;
        const float2 q0 = ((const float2*)w_pt0)[gi];
        const float pp = fmaf(q0.x, q0.x, q0.y * q0.y);   // |p|^2
        const float l2 = sqrtf(fmaxf(d + pp, 0.0f));

        const float thr = 8.0f * scale0[n * 2 + 0];
        const float sxd = ((float)W1C * scale1[n * 2 + 0] * 8.0f - 1.0f) * 0.5f;
        const float syd = ((float)H1C * scale1[n * 2 + 1] * 8.0f - 1.0f) * 0.5f;
        const float* im = score1 + (size_t)n * L1;

        // both mask interpretations (int32 and float32 agree on word != 0)
        const float mw = (((const u32*)maskp)[gi] != 0u) ? 1.0f : 0.0f;
        const float mb = (((const unsigned char*)maskp)[gi] != 0) ? 1.0f : 0.0f;
        const float inthr = (l2 <= thr) ? 1.0f : 0.0f;

        const float s0v  = score0[gi];
        const float ssum = im[jj] + s0v;

        // bilinear grid-sample of score1 as 60x80 image, zeros outside
        const float gx = (q0.x / sxd) * 0.5f * (float)(W1C - 1);
        const float gy = (q0.y / syd) * 0.5f * (float)(H1C - 1);
        const float x0 = floorf(gx), y0 = floorf(gy);
        const float x1 = x0 + 1.0f,  y1 = y0 + 1.0f;
        const float wx1 = gx - x0, wx0 = 1.0f - wx1;
        const float wy1 = gy - y0, wy0 = 1.0f - wy1;

        auto corner = [&](float xf, float yf) -> float {
            bool inb = (xf >= 0.0f) && (xf <= (float)(W1C - 1)) &&
                       (yf >= 0.0f) && (yf <= (float)(H1C - 1));
            int xc = (int)fminf(fmaxf(xf, 0.0f), (float)(W1C - 1));
            int yc = (int)fminf(fmaxf(yf, 0.0f), (float)(H1C - 1));
            float v = im[yc * W1C + xc];
            return inb ? v : 0.0f;
        };
        const float res = corner(x0, y0) * wx0 * wy0
                        + corner(x1, y0) * wx1 * wy0
                        + corner(x0, y1) * wx0 * wy1
                        + corner(x1, y1) * wx1 * wy1;
        const float dsc = res - s0v;
        const float dsq = dsc * dsc;

        const float dvw = inthr * mw, dvb = inthr * mb;
        float v0  = dvw,        v1 = l2 * dvw,  v2  = ssum * l2 * dvw;
        float v3  = ssum * dvw, v4 = mw,        v5  = dsq * mw;
        float v6  = dvb,        v7 = l2 * dvb,  v8  = ssum * l2 * dvb;
        float v9  = ssum * dvb, v10 = mb,       v11 = dsq * mb;
#define RED8(V) { V += __shfl_xor(V, 4); V += __shfl_xor(V, 2); V += __shfl_xor(V, 1); }
        RED8(v0) RED8(v1) RED8(v2) RED8(v3) RED8(v4)  RED8(v5)
        RED8(v6) RED8(v7) RED8(v8) RED8(v9) RED8(v10) RED8(v11)
#undef RED8
        if (tid == 0) {
            partials[ 0 * NBLK + blk] = v0;  partials[ 1 * NBLK + blk] = v1;
            partials[ 2 * NBLK + blk] = v2;  partials[ 3 * NBLK + blk] = v3;
            partials[ 4 * NBLK + blk] = v4;  partials[ 5 * NBLK + blk] = v5;
            partials[ 6 * NBLK + blk] = v6;  partials[ 7 * NBLK + blk] = v7;
            partials[ 8 * NBLK + blk] = v8;  partials[ 9 * NBLK + blk] = v9;
            partials[10 * NBLK + blk] = v10; partials[11 * NBLK + blk] = v11;
        }
    }
}

// ---------------------------------------------------------------------------
// Finalize: one block. Detects mask format, reduces 12 partial arrays, emits.
// ---------------------------------------------------------------------------
__global__ __launch_bounds__(NT) void s2ld_finalize(
    const float* __restrict__ partials,
    const void*  __restrict__ maskp,
    float*       __restrict__ out)
{
    __shared__ float fin[12 * NW];
    __shared__ u32   sbad;

    const int tid  = threadIdx.x;
    const int lane = tid & 63;
    const int wv   = tid >> 6;

    if (tid == 0) sbad = 0u;
    __syncthreads();
    {
        // mask format detection (first 2400 words in-bounds for all layouts)
        u32 bad = 0u;
        const u32* mwp = (const u32*)maskp;
        for (int i = tid; i < 2400; i += NT) {
            u32 w = mwp[i];
            if (w != 0u && w != 1u && w != 0x3f800000u) bad = 1u;
        }
        atomicOr(&sbad, bad);
    }

    for (int k = 0; k < 12; ++k) {
        float s = 0.0f;
        for (int rbl = tid; rbl < NBLK; rbl += NT) s += partials[k * NBLK + rbl];
        #pragma unroll
        for (int off = 32; off; off >>= 1) s += __shfl_xor(s, off);
        if (lane == 0) fin[k * NW + wv] = s;
    }
    __syncthreads();

    if (tid == 0) {
        const int o = (sbad == 0u) ? 0 : 6;   // word-format vs byte-format
        float S[6];
        #pragma unroll
        for (int k = 0; k < 6; ++k) {
            float s = 0.0f;
            #pragma unroll
            for (int w = 0; w < NW; ++w) s += fin[(o + k) * NW + w];
            S[k] = s;
        }
        const float den = fmaxf(S[0], 1.0f);
        const float lm  = S[1] / den;
        out[0] = lm;                              // loc_loss_mean
        out[1] = (S[2] - lm * S[3]) / den;        // rep_loss_mean
        out[2] = 2.0f * S[5] / fmaxf(S[4], 1.0f); // score_loss
    }
}

extern "C" void kernel_launch(void* const* d_in, const int* in_sizes, int n_in,
                              void* d_out, int out_size, void* d_ws, size_t ws_size,
                              hipStream_t stream) {
    const float* w_pt0  = (const float*)d_in[0];
    const float* pt1    = (const float*)d_in[1];
    const void*  maskp  =               d_in[2];
    const float* score0 = (const float*)d_in[3];
    const float* score1 = (const float*)d_in[4];
    // d_in[5] = image1 (zeros) -- unused
    const float* scale0 = (const float*)d_in[6];
    const float* scale1 = (const float*)d_in[7];

    float* partials = (float*)d_ws;   // 12 * 1200 * 4 B, fully rewritten

    s2ld_main<<<NBLK, NT, 0, stream>>>(w_pt0, pt1, maskp, score0, score1,
                                       scale0, scale1, partials);
    s2ld_finalize<<<1, NT, 0, stream>>>(partials, maskp, (float*)d_out);
}

// Round 10
// 40.078 us; speedup vs baseline: 1.5951x; 1.1515x over previous
//
#include <hip/hip_runtime.h>
#include <math.h>

typedef unsigned long long u64;
typedef unsigned int u32;

#define NB   2
#define L0   4800
#define L1   4800
#define H1C  60
#define W1C  80
#define ROWS 8
#define RPB  (L0 / ROWS)          // 600 row-groups per batch
#define NBLK (NB * RPB)           // 1200 blocks
#define NT   256                  // 4 waves
#define NW   (NT / 64)
#define CH4  1200                 // float4 per pass (2 passes x 1200 = 2400)
// partials layout: k in [0,12): {Sm,Sl2,Ssl2,Ss,Sv,Ssq} x {word-mask, byte-mask}

// ---------------------------------------------------------------------------
// Main kernel. r9 skeleton, three changes:
//  - LDS halved to 19.2KB (two serial passes over pt1, one buffer)
//    -> 8 blocks/CU by LDS; all ~4.7 available blocks/CU resident.
//  - u64-packed wave reduce (exact (min s, then min j) in cmp_u64+cndmask).
//  - epilogue recomputes exact d2 from pt1[jj] (kills fma-reassoc absmax).
// __launch_bounds__(256,6): VGPR cap ~84 > ~60 needed -> no spill, 6 w/SIMD.
// ---------------------------------------------------------------------------
__global__ __launch_bounds__(NT, 6) void s2ld_main(
    const float* __restrict__ w_pt0,    // [NB][L0][2]
    const float* __restrict__ pt1,      // [NB][L1][2]
    const void*  __restrict__ maskp,    // [NB][L0] word- or byte-bool
    const float* __restrict__ score0,   // [NB][L0]
    const float* __restrict__ score1,   // [NB][L1]
    const float* __restrict__ scale0,   // [NB][2]
    const float* __restrict__ scale1,   // [NB][2]
    float*       __restrict__ partials) // [12][NBLK]
{
    __shared__ float4 sF[CH4];          // 19200 B
    __shared__ u64    redk[ROWS * NW];  // 256 B

    const int tid  = threadIdx.x;
    const int blk  = blockIdx.x;
    // parity swizzle: blocks land on XCD (blk%8); stride-8 sets share parity,
    // so each XCD touches exactly one batch's pt1.
    const int n    = blk & 1;
    const int rg   = blk >> 1;          // row-group within batch, 0..599
    const int gi0  = n * L0 + rg * ROWS;
    const int lane = tid & 63;
    const int wv   = tid >> 6;

    const float4* p1 = (const float4*)(pt1 + (size_t)n * L1 * 2);
    const float2* p0 = (const float2*)(w_pt0 + (size_t)gi0 * 2);

    // minimize s_j = |q_j|^2 - 2 p.q_j (same order as d2); ax=-2px, ay=-2py.
    float ax[ROWS], ay[ROWS];
    #pragma unroll
    for (int r = 0; r < ROWS; ++r) {
        float2 q = p0[r];
        ax[r] = -2.0f * q.x; ay[r] = -2.0f * q.y;
    }
    float bd[ROWS]; int bj[ROWS];
    #pragma unroll
    for (int r = 0; r < ROWS; ++r) { bd[r] = 3.0e38f; bj[r] = 0; }

    // two serial passes over pt1, one 19.2KB buffer; j ascends per thread
    // => first-occurrence argmin within a thread.
    for (int p = 0; p < 2; ++p) {
        __syncthreads();                 // prior-pass readers done (no-op p=0)
        for (int k = tid; k < CH4; k += NT) sF[k] = p1[p * CH4 + k];
        __syncthreads();
        for (int j4 = tid; j4 < CH4; j4 += NT) {
            const float4 q = sF[j4];
            const float c0 = fmaf(q.x, q.x, q.y * q.y);
            const float c1 = fmaf(q.z, q.z, q.w * q.w);
            const int j0 = 2 * (p * CH4 + j4);
            #pragma unroll
            for (int r = 0; r < ROWS; ++r) {
                float s0 = fmaf(ax[r], q.x, fmaf(ay[r], q.y, c0));
                if (s0 < bd[r]) { bd[r] = s0; bj[r] = j0; }
                float s1 = fmaf(ax[r], q.z, fmaf(ay[r], q.w, c1));
                if (s1 < bd[r]) { bd[r] = s1; bj[r] = j0 + 1; }
            }
        }
    }

    // pack (monotone-transformed s, j) into u64: min_u64 == (min s, then min j)
    #pragma unroll
    for (int r = 0; r < ROWS; ++r) {
        u32 b = __float_as_uint(bd[r]);
        u32 t = b ^ ((u32)((int)b >> 31) | 0x80000000u);   // IEEE->monotone u32
        u64 key = ((u64)t << 32) | (u32)bj[r];
        #pragma unroll
        for (int off = 32; off; off >>= 1) {
            u64 ok = __shfl_xor(key, off);
            if (ok < key) key = ok;
        }
        if (lane == 0) redk[r * NW + wv] = key;
    }
    __syncthreads();

    // parallel epilogue: lane r (< 8, wave 0) handles row r
    if (tid < ROWS) {
        const int r = tid;
        u64 key = redk[r * NW + 0];
        #pragma unroll
        for (int w = 1; w < NW; ++w) {
            u64 ok = redk[r * NW + w];
            if (ok < key) key = ok;
        }
        const int jj = (int)(u32)key;
        const int gi = gi0 + r;
        const float2 q0 = ((const float2*)w_pt0)[gi];
        const float2 q1 = ((const float2*)(pt1 + (size_t)n * L1 * 2))[jj];
        const float dx = q0.x - q1.x, dy = q0.y - q1.y;
        const float l2 = sqrtf(dx * dx + dy * dy);         // exact d2

        const float thr = 8.0f * scale0[n * 2 + 0];
        const float sxd = ((float)W1C * scale1[n * 2 + 0] * 8.0f - 1.0f) * 0.5f;
        const float syd = ((float)H1C * scale1[n * 2 + 1] * 8.0f - 1.0f) * 0.5f;
        const float* im = score1 + (size_t)n * L1;

        // both mask interpretations (int32 and float32 agree on word != 0)
        const float mw = (((const u32*)maskp)[gi] != 0u) ? 1.0f : 0.0f;
        const float mb = (((const unsigned char*)maskp)[gi] != 0) ? 1.0f : 0.0f;
        const float inthr = (l2 <= thr) ? 1.0f : 0.0f;

        const float s0v  = score0[gi];
        const float ssum = im[jj] + s0v;

        // bilinear grid-sample of score1 as 60x80 image, zeros outside
        const float gx = (q0.x / sxd) * 0.5f * (float)(W1C - 1);
        const float gy = (q0.y / syd) * 0.5f * (float)(H1C - 1);
        const float x0 = floorf(gx), y0 = floorf(gy);
        const float x1 = x0 + 1.0f,  y1 = y0 + 1.0f;
        const float wx1 = gx - x0, wx0 = 1.0f - wx1;
        const float wy1 = gy - y0, wy0 = 1.0f - wy1;

        auto corner = [&](float xf, float yf) -> float {
            bool inb = (xf >= 0.0f) && (xf <= (float)(W1C - 1)) &&
                       (yf >= 0.0f) && (yf <= (float)(H1C - 1));
            int xc = (int)fminf(fmaxf(xf, 0.0f), (float)(W1C - 1));
            int yc = (int)fminf(fmaxf(yf, 0.0f), (float)(H1C - 1));
            float v = im[yc * W1C + xc];
            return inb ? v : 0.0f;
        };
        const float res = corner(x0, y0) * wx0 * wy0
                        + corner(x1, y0) * wx1 * wy0
                        + corner(x0, y1) * wx0 * wy1
                        + corner(x1, y1) * wx1 * wy1;
        const float dsc = res - s0v;
        const float dsq = dsc * dsc;

        const float dvw = inthr * mw, dvb = inthr * mb;
        float v0  = dvw,        v1 = l2 * dvw,  v2  = ssum * l2 * dvw;
        float v3  = ssum * dvw, v4 = mw,        v5  = dsq * mw;
        float v6  = dvb,        v7 = l2 * dvb,  v8  = ssum * l2 * dvb;
        float v9  = ssum * dvb, v10 = mb,       v11 = dsq * mb;
#define RED8(V) { V += __shfl_xor(V, 4); V += __shfl_xor(V, 2); V += __shfl_xor(V, 1); }
        RED8(v0) RED8(v1) RED8(v2) RED8(v3) RED8(v4)  RED8(v5)
        RED8(v6) RED8(v7) RED8(v8) RED8(v9) RED8(v10) RED8(v11)
#undef RED8
        if (tid == 0) {
            partials[ 0 * NBLK + blk] = v0;  partials[ 1 * NBLK + blk] = v1;
            partials[ 2 * NBLK + blk] = v2;  partials[ 3 * NBLK + blk] = v3;
            partials[ 4 * NBLK + blk] = v4;  partials[ 5 * NBLK + blk] = v5;
            partials[ 6 * NBLK + blk] = v6;  partials[ 7 * NBLK + blk] = v7;
            partials[ 8 * NBLK + blk] = v8;  partials[ 9 * NBLK + blk] = v9;
            partials[10 * NBLK + blk] = v10; partials[11 * NBLK + blk] = v11;
        }
    }
}

// ---------------------------------------------------------------------------
// Finalize: one block. Detects mask format, reduces 12 partial arrays, emits.
// ---------------------------------------------------------------------------
__global__ __launch_bounds__(NT) void s2ld_finalize(
    const float* __restrict__ partials,
    const void*  __restrict__ maskp,
    float*       __restrict__ out)
{
    __shared__ float fin[12 * NW];
    __shared__ u32   sbad;

    const int tid  = threadIdx.x;
    const int lane = tid & 63;
    const int wv   = tid >> 6;

    if (tid == 0) sbad = 0u;
    __syncthreads();
    {
        // mask format detection (first 2400 words in-bounds for all layouts)
        u32 bad = 0u;
        const u32* mwp = (const u32*)maskp;
        for (int i = tid; i < 2400; i += NT) {
            u32 w = mwp[i];
            if (w != 0u && w != 1u && w != 0x3f800000u) bad = 1u;
        }
        atomicOr(&sbad, bad);
    }

    for (int k = 0; k < 12; ++k) {
        float s = 0.0f;
        for (int rbl = tid; rbl < NBLK; rbl += NT) s += partials[k * NBLK + rbl];
        #pragma unroll
        for (int off = 32; off; off >>= 1) s += __shfl_xor(s, off);
        if (lane == 0) fin[k * NW + wv] = s;
    }
    __syncthreads();

    if (tid == 0) {
        const int o = (sbad == 0u) ? 0 : 6;   // word-format vs byte-format
        float S[6];
        #pragma unroll
        for (int k = 0; k < 6; ++k) {
            float s = 0.0f;
            #pragma unroll
            for (int w = 0; w < NW; ++w) s += fin[(o + k) * NW + w];
            S[k] = s;
        }
        const float den = fmaxf(S[0], 1.0f);
        const float lm  = S[1] / den;
        out[0] = lm;                              // loc_loss_mean
        out[1] = (S[2] - lm * S[3]) / den;        // rep_loss_mean
        out[2] = 2.0f * S[5] / fmaxf(S[4], 1.0f); // score_loss
    }
}

extern "C" void kernel_launch(void* const* d_in, const int* in_sizes, int n_in,
                              void* d_out, int out_size, void* d_ws, size_t ws_size,
                              hipStream_t stream) {
    const float* w_pt0  = (const float*)d_in[0];
    const float* pt1    = (const float*)d_in[1];
    const void*  maskp  =               d_in[2];
    const float* score0 = (const float*)d_in[3];
    const float* score1 = (const float*)d_in[4];
    // d_in[5] = image1 (zeros) -- unused
    const float* scale0 = (const float*)d_in[6];
    const float* scale1 = (const float*)d_in[7];

    float* partials = (float*)d_ws;   // 12 * 1200 * 4 B, fully rewritten

    s2ld_main<<<NBLK, NT, 0, stream>>>(w_pt0, pt1, maskp, score0, score1,
                                       scale0, scale1, partials);
    s2ld_finalize<<<1, NT, 0, stream>>>(partials, maskp, (float*)d_out);
}

// Round 11
// 39.711 us; speedup vs baseline: 1.6098x; 1.0093x over previous
//
#include <hip/hip_runtime.h>
#include <math.h>

typedef unsigned long long u64;
typedef unsigned int u32;

#define NB   2
#define L0   4800
#define L1   4800
#define H1C  60
#define W1C  80
#define ROWS 8
#define RPB  (L0 / ROWS)          // 600 row-groups per batch
#define NBLK (NB * RPB)           // 1200 blocks
#define NT   256                  // 4 waves
#define NW   (NT / 64)
#define L14  (L1 / 2)             // 2400 float4 per batch
// partials layout: k in [0,12): {Sm,Sl2,Ssl2,Ss,Sv,Ssq} x {word-mask, byte-mask}

// ---------------------------------------------------------------------------
// Main kernel -- direct-L2 ablation of the LDS-staging barrier pattern.
// pt1 is 38.4KB/batch: fully L2-resident; 1200 blocks re-reading it is 46MB
// of L2 traffic (~1.3us at L2 BW) -- staging was only ever a latency device,
// and its __syncthreads() correlates all 4 waves of a block on the slowest
// load. Here: zero barriers before the reduce; 9.4 independent float4 L2
// loads per thread, latency hidden by TLP (16 waves/CU).
// __launch_bounds__(256,4): the only cap proven spill-free (r1/r6/r7);
// (256,8) and bare bounds force VGPR->32 + scratch (r4/r8, WRITE=487KB).
// ---------------------------------------------------------------------------
__global__ __launch_bounds__(NT, 4) void s2ld_main(
    const float* __restrict__ w_pt0,    // [NB][L0][2]
    const float* __restrict__ pt1,      // [NB][L1][2]
    const void*  __restrict__ maskp,    // [NB][L0] word- or byte-bool
    const float* __restrict__ score0,   // [NB][L0]
    const float* __restrict__ score1,   // [NB][L1]
    const float* __restrict__ scale0,   // [NB][2]
    const float* __restrict__ scale1,   // [NB][2]
    float*       __restrict__ partials) // [12][NBLK]
{
    __shared__ u64 redk[ROWS * NW];     // 256 B -- only LDS in the kernel

    const int tid  = threadIdx.x;
    const int blk  = blockIdx.x;
    // parity swizzle: stride-8 XCD round-robin keeps each XCD on one batch's pt1
    const int n    = blk & 1;
    const int rg   = blk >> 1;          // row-group within batch, 0..599
    const int gi0  = n * L0 + rg * ROWS;
    const int lane = tid & 63;
    const int wv   = tid >> 6;

    const float4* p1 = (const float4*)(pt1 + (size_t)n * L1 * 2);
    const float2* p0 = (const float2*)(w_pt0 + (size_t)gi0 * 2);

    // minimize s_j = |q_j|^2 - 2 p.q_j (same order as d2); ax=-2px, ay=-2py.
    float ax[ROWS], ay[ROWS];
    #pragma unroll
    for (int r = 0; r < ROWS; ++r) {
        float2 q = p0[r];
        ax[r] = -2.0f * q.x; ay[r] = -2.0f * q.y;
    }
    float bd[ROWS]; int bj[ROWS];
    #pragma unroll
    for (int r = 0; r < ROWS; ++r) { bd[r] = 3.0e38f; bj[r] = 0; }

    // direct-L2 stream over pt1; j ascends per thread => first-occurrence
    // argmin within a thread; cross-thread ties resolved in the u64 reduce.
    for (int j4 = tid; j4 < L14; j4 += NT) {
        const float4 q = p1[j4];
        const float c0 = fmaf(q.x, q.x, q.y * q.y);
        const float c1 = fmaf(q.z, q.z, q.w * q.w);
        const int j0 = 2 * j4;
        #pragma unroll
        for (int r = 0; r < ROWS; ++r) {
            float s0 = fmaf(ax[r], q.x, fmaf(ay[r], q.y, c0));
            if (s0 < bd[r]) { bd[r] = s0; bj[r] = j0; }
            float s1 = fmaf(ax[r], q.z, fmaf(ay[r], q.w, c1));
            if (s1 < bd[r]) { bd[r] = s1; bj[r] = j0 + 1; }
        }
    }

    // pack (monotone-transformed s, j) into u64: min_u64 == (min s, then min j)
    #pragma unroll
    for (int r = 0; r < ROWS; ++r) {
        u32 b = __float_as_uint(bd[r]);
        u32 t = b ^ ((u32)((int)b >> 31) | 0x80000000u);   // IEEE->monotone u32
        u64 key = ((u64)t << 32) | (u32)bj[r];
        #pragma unroll
        for (int off = 32; off; off >>= 1) {
            u64 ok = __shfl_xor(key, off);
            if (ok < key) key = ok;
        }
        if (lane == 0) redk[r * NW + wv] = key;
    }
    __syncthreads();                    // the kernel's only barrier

    // parallel epilogue: lane r (< 8, wave 0) handles row r
    if (tid < ROWS) {
        const int r = tid;
        u64 key = redk[r * NW + 0];
        #pragma unroll
        for (int w = 1; w < NW; ++w) {
            u64 ok = redk[r * NW + w];
            if (ok < key) key = ok;
        }
        const int jj = (int)(u32)key;
        const int gi = gi0 + r;
        const float2 q0 = ((const float2*)w_pt0)[gi];
        const float2 q1 = ((const float2*)(pt1 + (size_t)n * L1 * 2))[jj];
        const float dx = q0.x - q1.x, dy = q0.y - q1.y;
        const float l2 = sqrtf(dx * dx + dy * dy);         // exact d2

        const float thr = 8.0f * scale0[n * 2 + 0];
        const float sxd = ((float)W1C * scale1[n * 2 + 0] * 8.0f - 1.0f) * 0.5f;
        const float syd = ((float)H1C * scale1[n * 2 + 1] * 8.0f - 1.0f) * 0.5f;
        const float* im = score1 + (size_t)n * L1;

        // both mask interpretations (int32 and float32 agree on word != 0)
        const float mw = (((const u32*)maskp)[gi] != 0u) ? 1.0f : 0.0f;
        const float mb = (((const unsigned char*)maskp)[gi] != 0) ? 1.0f : 0.0f;
        const float inthr = (l2 <= thr) ? 1.0f : 0.0f;

        const float s0v  = score0[gi];
        const float ssum = im[jj] + s0v;

        // bilinear grid-sample of score1 as 60x80 image, zeros outside
        const float gx = (q0.x / sxd) * 0.5f * (float)(W1C - 1);
        const float gy = (q0.y / syd) * 0.5f * (float)(H1C - 1);
        const float x0 = floorf(gx), y0 = floorf(gy);
        const float x1 = x0 + 1.0f,  y1 = y0 + 1.0f;
        const float wx1 = gx - x0, wx0 = 1.0f - wx1;
        const float wy1 = gy - y0, wy0 = 1.0f - wy1;

        auto corner = [&](float xf, float yf) -> float {
            bool inb = (xf >= 0.0f) && (xf <= (float)(W1C - 1)) &&
                       (yf >= 0.0f) && (yf <= (float)(H1C - 1));
            int xc = (int)fminf(fmaxf(xf, 0.0f), (float)(W1C - 1));
            int yc = (int)fminf(fmaxf(yf, 0.0f), (float)(H1C - 1));
            float v = im[yc * W1C + xc];
            return inb ? v : 0.0f;
        };
        const float res = corner(x0, y0) * wx0 * wy0
                        + corner(x1, y0) * wx1 * wy0
                        + corner(x0, y1) * wx0 * wy1
                        + corner(x1, y1) * wx1 * wy1;
        const float dsc = res - s0v;
        const float dsq = dsc * dsc;

        const float dvw = inthr * mw, dvb = inthr * mb;
        float v0  = dvw,        v1 = l2 * dvw,  v2  = ssum * l2 * dvw;
        float v3  = ssum * dvw, v4 = mw,        v5  = dsq * mw;
        float v6  = dvb,        v7 = l2 * dvb,  v8  = ssum * l2 * dvb;
        float v9  = ssum * dvb, v10 = mb,       v11 = dsq * mb;
#define RED8(V) { V += __shfl_xor(V, 4); V += __shfl_xor(V, 2); V += __shfl_xor(V, 1); }
        RED8(v0) RED8(v1) RED8(v2) RED8(v3) RED8(v4)  RED8(v5)
        RED8(v6) RED8(v7) RED8(v8) RED8(v9) RED8(v10) RED8(v11)
#undef RED8
        if (tid == 0) {
            partials[ 0 * NBLK + blk] = v0;  partials[ 1 * NBLK + blk] = v1;
            partials[ 2 * NBLK + blk] = v2;  partials[ 3 * NBLK + blk] = v3;
            partials[ 4 * NBLK + blk] = v4;  partials[ 5 * NBLK + blk] = v5;
            partials[ 6 * NBLK + blk] = v6;  partials[ 7 * NBLK + blk] = v7;
            partials[ 8 * NBLK + blk] = v8;  partials[ 9 * NBLK + blk] = v9;
            partials[10 * NBLK + blk] = v10; partials[11 * NBLK + blk] = v11;
        }
    }
}

// ---------------------------------------------------------------------------
// Finalize: one block. Detects mask format, reduces 12 partial arrays, emits.
// ---------------------------------------------------------------------------
__global__ __launch_bounds__(NT) void s2ld_finalize(
    const float* __restrict__ partials,
    const void*  __restrict__ maskp,
    float*       __restrict__ out)
{
    __shared__ float fin[12 * NW];
    __shared__ u32   sbad;

    const int tid  = threadIdx.x;
    const int lane = tid & 63;
    const int wv   = tid >> 6;

    if (tid == 0) sbad = 0u;
    __syncthreads();
    {
        // mask format detection (first 2400 words in-bounds for all layouts)
        u32 bad = 0u;
        const u32* mwp = (const u32*)maskp;
        for (int i = tid; i < 2400; i += NT) {
            u32 w = mwp[i];
            if (w != 0u && w != 1u && w != 0x3f800000u) bad = 1u;
        }
        atomicOr(&sbad, bad);
    }

    for (int k = 0; k < 12; ++k) {
        float s = 0.0f;
        for (int rbl = tid; rbl < NBLK; rbl += NT) s += partials[k * NBLK + rbl];
        #pragma unroll
        for (int off = 32; off; off >>= 1) s += __shfl_xor(s, off);
        if (lane == 0) fin[k * NW + wv] = s;
    }
    __syncthreads();

    if (tid == 0) {
        const int o = (sbad == 0u) ? 0 : 6;   // word-format vs byte-format
        float S[6];
        #pragma unroll
        for (int k = 0; k < 6; ++k) {
            float s = 0.0f;
            #pragma unroll
            for (int w = 0; w < NW; ++w) s += fin[(o + k) * NW + w];
            S[k] = s;
        }
        const float den = fmaxf(S[0], 1.0f);
        const float lm  = S[1] / den;
        out[0] = lm;                              // loc_loss_mean
        out[1] = (S[2] - lm * S[3]) / den;        // rep_loss_mean
        out[2] = 2.0f * S[5] / fmaxf(S[4], 1.0f); // score_loss
    }
}

extern "C" void kernel_launch(void* const* d_in, const int* in_sizes, int n_in,
                              void* d_out, int out_size, void* d_ws, size_t ws_size,
                              hipStream_t stream) {
    const float* w_pt0  = (const float*)d_in[0];
    const float* pt1    = (const float*)d_in[1];
    const void*  maskp  =               d_in[2];
    const float* score0 = (const float*)d_in[3];
    const float* score1 = (const float*)d_in[4];
    // d_in[5] = image1 (zeros) -- unused
    const float* scale0 = (const float*)d_in[6];
    const float* scale1 = (const float*)d_in[7];

    float* partials = (float*)d_ws;   // 12 * 1200 * 4 B, fully rewritten

    s2ld_main<<<NBLK, NT, 0, stream>>>(w_pt0, pt1, maskp, score0, score1,
                                       scale0, scale1, partials);
    s2ld_finalize<<<1, NT, 0, stream>>>(partials, maskp, (float*)d_out);
}